// Round 8
// baseline (86.680 us; speedup 1.0000x reference)
//
#include <hip/hip_runtime.h>
#include <stdint.h>

#define NN 8192
#define NE 8192
#define DIM 256
#define NW 128   // 64-bit words per adjacency row (8192 bits)
#define HCAP 64  // max common neighbors; worst case i==j -> deg_max ~55
#define TE 64    // edges per block (fused); 128 blocks

typedef short bf16x8 __attribute__((ext_vector_type(8)));
typedef float f32x4 __attribute__((ext_vector_type(4)));

__device__ __forceinline__ unsigned short f2bf(float f) {
  uint32_t u = __builtin_bit_cast(uint32_t, f);
  u += 0x7fffu + ((u >> 16) & 1u);   // round-to-nearest-even
  return (unsigned short)(u >> 16);
}
__device__ __forceinline__ float bf2f(unsigned short h) {
  uint32_t u = ((uint32_t)h) << 16;
  return __builtin_bit_cast(float, u);
}

// ============ prep: weight transpose (blocks 0..1535) + adj pack (rest) ====
// Pack bit layout: task t covers row r = t>>5, segment s = t&31 (256 cols).
// Lane l loads float4 at cols s*256 + 4l .. 4l+3. ballot(component q) ->
// word bits[r*128 + s*4 + q], bit l  <->  col = s*256 + 4*l + q.
__global__ __launch_bounds__(256) void prep_kernel(
    const float* __restrict__ adj,
    const float* __restrict__ W1c, const float* __restrict__ W2c,
    const float* __restrict__ W1j, const float* __restrict__ W2j,
    const float* __restrict__ Wl1, const float* __restrict__ Wl2,
    unsigned short* __restrict__ Wt,
    unsigned long long* __restrict__ bits) {
  const int blk = blockIdx.x;
  if (blk < 1536) {
    // Wt[w][n][k] = W[w][k][n], bf16
    const float* Ws[6] = {W1c, W2c, W1j, W2j, Wl1, Wl2};
    const int w = blk >> 8;
    const int n = blk & 255;
    const int k = threadIdx.x;
    Wt[w * 65536 + n * DIM + k] = f2bf(Ws[w][k * DIM + n]);
  } else {
    const float4* __restrict__ adjv = (const float4*)adj;
    const int lane = threadIdx.x & 63;
    const int wv = (blk - 1536) * 4 + (threadIdx.x >> 6);
    const int nwv = 4096 * 4;
    const int total = NN * 32;  // float4-tasks
    // 4 tasks per iter (4 KB in flight per wave); t%4==0 -> one row,
    // 16 contiguous u64 words to store.
    for (int t = 4 * wv; t < total; t += 4 * nwv) {
      float4 v0 = adjv[(size_t)((t + 0) >> 5) * 2048 + ((t + 0) & 31) * 64 + lane];
      float4 v1 = adjv[(size_t)((t + 1) >> 5) * 2048 + ((t + 1) & 31) * 64 + lane];
      float4 v2 = adjv[(size_t)((t + 2) >> 5) * 2048 + ((t + 2) & 31) * 64 + lane];
      float4 v3 = adjv[(size_t)((t + 3) >> 5) * 2048 + ((t + 3) & 31) * 64 + lane];
      unsigned long long m00 = __ballot(v0.x != 0.0f);
      unsigned long long m01 = __ballot(v0.y != 0.0f);
      unsigned long long m02 = __ballot(v0.z != 0.0f);
      unsigned long long m03 = __ballot(v0.w != 0.0f);
      unsigned long long m10 = __ballot(v1.x != 0.0f);
      unsigned long long m11 = __ballot(v1.y != 0.0f);
      unsigned long long m12 = __ballot(v1.z != 0.0f);
      unsigned long long m13 = __ballot(v1.w != 0.0f);
      unsigned long long m20 = __ballot(v2.x != 0.0f);
      unsigned long long m21 = __ballot(v2.y != 0.0f);
      unsigned long long m22 = __ballot(v2.z != 0.0f);
      unsigned long long m23 = __ballot(v2.w != 0.0f);
      unsigned long long m30 = __ballot(v3.x != 0.0f);
      unsigned long long m31 = __ballot(v3.y != 0.0f);
      unsigned long long m32 = __ballot(v3.z != 0.0f);
      unsigned long long m33 = __ballot(v3.w != 0.0f);
      if (lane == 0) {
        unsigned long long* p = bits + (size_t)(t >> 5) * NW + (t & 31) * 4;
        p[0]  = m00; p[1]  = m01; p[2]  = m02; p[3]  = m03;
        p[4]  = m10; p[5]  = m11; p[6]  = m12; p[7]  = m13;
        p[8]  = m20; p[9]  = m21; p[10] = m22; p[11] = m23;
        p[12] = m30; p[13] = m31; p[14] = m32; p[15] = m33;
      }
    }
  }
}

// ================= fused: CN intersect + xixj + 5-GEMM chain + GEMV ========
// Block: 1024 threads = 16 waves, TE=64 edges, 128 blocks.
// Each wave owns 16 output cols (1 n-tile) x 4 m-tiles of 16 rows.
// A-frag: row = lane&15, k = (lane>>4)*8 + j
// B-frag: col = lane&15, k = (lane>>4)*8 + j  (register-resident, prefetched)
// C/D:    col = lane&15, row = (lane>>4)*4 + reg   (m89-verified)
// Phase-fused S2+S4: acc = U1@W2c + U2@W2j in one phase (one barrier).

#define LDP 264  // 256 + 8 bf16 pad (row stride 528 B, 2-way bank alias = free)

__device__ __forceinline__ void load_w16(const unsigned short* __restrict__ Wt,
                                         bf16x8 w[8], int lane, int wave) {
  const int lr = lane & 15;
  const int kl = (lane >> 4) * 8;
  const int n0 = wave * 16;
#pragma unroll
  for (int kk = 0; kk < 8; ++kk)
    w[kk] = *(const bf16x8*)(Wt + (size_t)(n0 + lr) * DIM + kk * 32 + kl);
}

__device__ __forceinline__ void gemm64(const unsigned short (*src)[LDP],
                                       const bf16x8 w[8],
                                       f32x4 acc[4], int lane) {
  const int lr = lane & 15;
  const int kl = (lane >> 4) * 8;
#pragma unroll
  for (int kk = 0; kk < 8; ++kk) {
    const int k0 = kk * 32 + kl;
    bf16x8 a0 = *(const bf16x8*)(&src[lr][k0]);
    bf16x8 a1 = *(const bf16x8*)(&src[16 + lr][k0]);
    bf16x8 a2 = *(const bf16x8*)(&src[32 + lr][k0]);
    bf16x8 a3 = *(const bf16x8*)(&src[48 + lr][k0]);
    acc[0] = __builtin_amdgcn_mfma_f32_16x16x32_bf16(a0, w[kk], acc[0], 0, 0, 0);
    acc[1] = __builtin_amdgcn_mfma_f32_16x16x32_bf16(a1, w[kk], acc[1], 0, 0, 0);
    acc[2] = __builtin_amdgcn_mfma_f32_16x16x32_bf16(a2, w[kk], acc[2], 0, 0, 0);
    acc[3] = __builtin_amdgcn_mfma_f32_16x16x32_bf16(a3, w[kk], acc[3], 0, 0, 0);
  }
}

__device__ __forceinline__ void zero4(f32x4 a[4]) {
  const f32x4 z = {0.f, 0.f, 0.f, 0.f};
  a[0] = z; a[1] = z; a[2] = z; a[3] = z;
}

__device__ __forceinline__ void epilogue64(f32x4 acc[4], float bb, bool relu,
                                           unsigned short (*dst)[LDP],
                                           int lane, int wave) {
  const int lc = lane & 15;
  const int rg = (lane >> 4) * 4;
  const int col = wave * 16 + lc;
#pragma unroll
  for (int m = 0; m < 4; ++m)
#pragma unroll
    for (int q = 0; q < 4; ++q) {
      float v = acc[m][q] + bb;
      if (relu) v = fmaxf(v, 0.f);
      dst[m * 16 + rg + q][col] = f2bf(v);
    }
}

__global__ __launch_bounds__(1024) void fused_kernel(
    const float* __restrict__ x,
    const unsigned long long* __restrict__ bits,
    const int* __restrict__ tar,
    const unsigned short* __restrict__ Wt,
    const float* __restrict__ b1c, const float* __restrict__ b2c,
    const float* __restrict__ b1j, const float* __restrict__ b2j,
    const float* __restrict__ bl1, const float* __restrict__ bl2,
    const float* __restrict__ Wout, const float* __restrict__ bout,
    float* __restrict__ out) {
  __shared__ unsigned short lA[TE][LDP];  // xcn -> U2 -> h2
  __shared__ unsigned short lB[TE][LDP];  // U1 -> h3
  __shared__ unsigned short lC[TE][LDP];  // xixj -> h
  __shared__ int hits[TE][HCAP];
  __shared__ int nh[TE];

  const int tid = threadIdx.x;
  const int lane = tid & 63;
  const int wave = tid >> 6;  // 0..15
  const int e0 = blockIdx.x * TE;

  // ---- per-lane bias preloads (5 scalars) ----
  const int lc = lane & 15;
  const int c0 = wave * 16 + lc;
  const float vb1c = b1c[c0];
  const float vb1j = b1j[c0];
  const float vb2 = b2c[c0] + b2j[c0];
  const float vbl1 = bl1[c0];
  const float vbl2 = bl2[c0];

  if (tid < TE) nh[tid] = 0;

  // ---- (a) bits words -> regs (16 thr/edge, 8 words each endpoint) ----
  const int e_a = tid >> 4;
  const int t16 = tid & 15;
  unsigned long long bw_i[8], bw_j[8];
  {
    const int ia = tar[e0 + e_a];
    const int ja = tar[NE + e0 + e_a];
    const unsigned long long* bi = bits + (size_t)ia * NW + t16 * 8;
    const unsigned long long* bj = bits + (size_t)ja * NW + t16 * 8;
#pragma unroll
    for (int q = 0; q < 8; ++q) { bw_i[q] = bi[q]; bw_j[q] = bj[q]; }
  }

  // ---- (b) xixj -> lC (independent; hides (a)'s latency) ----
  {
    const int col = tid & 255;
    const int sub = tid >> 8;  // 0..3 -> 16 edges each
    float vi[16], vj[16];
#pragma unroll
    for (int p = 0; p < 16; ++p) {
      const int e = sub * 16 + p;
      vi[p] = x[(size_t)tar[e0 + e] * DIM + col];
      vj[p] = x[(size_t)tar[NE + e0 + e] * DIM + col];
    }
#pragma unroll
    for (int p = 0; p < 16; ++p)
      lC[sub * 16 + p][col] = f2bf(vi[p] * vj[p]);
  }
  __syncthreads();  // nh zeroed; (a)/(b) loads drained

  // ---- (c) intersect (pure VALU + LDS atomics) ----
  // word w = t16*8+q -> base col = (w>>2)<<8, node = base + 4*bit + (w&3)
#pragma unroll
  for (int q = 0; q < 8; ++q) {
    unsigned long long m = bw_i[q] & bw_j[q];
    const int w = t16 * 8 + q;
    const int base = (w >> 2) << 8;
    const int qq = w & 3;
    while (m) {
      int b = __builtin_ctzll(m);
      m &= m - 1;
      int idx = atomicAdd(&nh[e_a], 1);
      if (idx < HCAP) hits[e_a][idx] = base + (b << 2) + qq;  // node id
    }
  }
  __syncthreads();

  // ---- prefetch W1c->wX, W2c->wY ; xcn gathers -> lA ----
  bf16x8 wX[8], wY[8];
  load_w16(Wt + 0 * 65536, wX, lane, wave);
  load_w16(Wt + 1 * 65536, wY, lane, wave);
  {
    const int col = tid & 255;
    const int sub = tid >> 8;
#pragma unroll
    for (int p = 0; p < 16; ++p) {
      const int e = sub * 16 + p;
      const int n = nh[e] < HCAP ? nh[e] : HCAP;
      float xc = 0.f;
      for (int h = 0; h < n; ++h)
        xc += x[(size_t)hits[e][h] * DIM + col];
      lA[e][col] = f2bf(xc);
    }
  }
  __syncthreads();

  f32x4 acc[4];

  // ---- P1: U1 = relu(xcn @ W1c + b1c) -> lB ; reload wX = W1j ----
  zero4(acc);
  gemm64(lA, wX, acc, lane);
  load_w16(Wt + 2 * 65536, wX, lane, wave);
  epilogue64(acc, vb1c, true, lB, lane, wave);
  __syncthreads();

  // ---- P2: U2 = relu(xixj @ W1j + b1j) -> lA ; reload wX = W2j ----
  zero4(acc);
  gemm64(lC, wX, acc, lane);
  load_w16(Wt + 3 * 65536, wX, lane, wave);
  epilogue64(acc, vb1j, true, lA, lane, wave);
  __syncthreads();

  // ---- P3: h = U1@W2c + U2@W2j + (b2c+b2j) -> lC (no relu) ----
  zero4(acc);
  gemm64(lB, wY, acc, lane);
  gemm64(lA, wX, acc, lane);
  load_w16(Wt + 4 * 65536, wY, lane, wave);  // Wl1
  load_w16(Wt + 5 * 65536, wX, lane, wave);  // Wl2
  epilogue64(acc, vb2, false, lC, lane, wave);
  __syncthreads();

  // ---- P4: h2 = relu(h @ Wl1 + bl1) -> lA ----
  zero4(acc);
  gemm64(lC, wY, acc, lane);
  epilogue64(acc, vbl1, true, lA, lane, wave);
  __syncthreads();

  // ---- P5: h3 = relu(h2 @ Wl2 + bl2) -> lB ----
  zero4(acc);
  gemm64(lA, wX, acc, lane);
  epilogue64(acc, vbl2, true, lB, lane, wave);
  __syncthreads();

  // ---- GEMV: out = h3 @ Wout + bout (16 thr/edge, 16 cols each) ----
  {
    const int el = tid >> 4;      // 0..63
    const int gp = tid & 15;      // 0..15
    const float4* __restrict__ w4 = (const float4*)Wout;
    float s = 0.f;
#pragma unroll
    for (int q4 = 0; q4 < 4; ++q4) {
      const float4 wq = w4[gp * 4 + q4];
      const int c = gp * 16 + q4 * 4;
      s += bf2f(lB[el][c + 0]) * wq.x + bf2f(lB[el][c + 1]) * wq.y +
           bf2f(lB[el][c + 2]) * wq.z + bf2f(lB[el][c + 3]) * wq.w;
    }
#pragma unroll
    for (int o = 8; o; o >>= 1) s += __shfl_xor(s, o);
    if (gp == 0) out[e0 + el] = s + bout[0];
  }
}

extern "C" void kernel_launch(void* const* d_in, const int* in_sizes, int n_in,
                              void* d_out, int out_size, void* d_ws, size_t ws_size,
                              hipStream_t stream) {
  const float* x    = (const float*)d_in[0];
  const float* adj  = (const float*)d_in[1];
  const int*   tar  = (const int*)d_in[2];
  const float* W1c  = (const float*)d_in[3];
  const float* b1c  = (const float*)d_in[4];
  const float* W2c  = (const float*)d_in[5];
  const float* b2c  = (const float*)d_in[6];
  const float* W1j  = (const float*)d_in[7];
  const float* b1j  = (const float*)d_in[8];
  const float* W2j  = (const float*)d_in[9];
  const float* b2j  = (const float*)d_in[10];
  const float* Wl1  = (const float*)d_in[11];
  const float* bl1  = (const float*)d_in[12];
  const float* Wl2  = (const float*)d_in[13];
  const float* bl2  = (const float*)d_in[14];
  const float* Wout = (const float*)d_in[15];
  const float* bout = (const float*)d_in[16];

  char* ws = (char*)d_ws;
  unsigned short*     Wt   = (unsigned short*)(ws);                  // 768 KB
  unsigned long long* bits = (unsigned long long*)(ws + (1u << 20)); // 8 MB

  prep_kernel<<<1536 + 4096, 256, 0, stream>>>(adj, W1c, W2c, W1j, W2j, Wl1,
                                               Wl2, Wt, bits);

  fused_kernel<<<NE / TE, 1024, 0, stream>>>(x, bits, tar, Wt, b1c, b2c, b1j,
                                             b2j, bl1, bl2, Wout, bout,
                                             (float*)d_out);
}

// Round 9
// 79.747 us; speedup vs baseline: 1.0869x; 1.0869x over previous
//
#include <hip/hip_runtime.h>
#include <stdint.h>

#define NN 8192
#define NE 8192
#define DIM 256
#define NW 128   // 64-bit words per adjacency row (8192 bits)
#define HCAP 64  // max common neighbors; worst case i==j -> deg_max ~55
#define TE 32    // edges per block (fused)

typedef short bf16x8 __attribute__((ext_vector_type(8)));
typedef float f32x4 __attribute__((ext_vector_type(4)));

__device__ __forceinline__ unsigned short f2bf(float f) {
  uint32_t u = __builtin_bit_cast(uint32_t, f);
  u += 0x7fffu + ((u >> 16) & 1u);   // round-to-nearest-even
  return (unsigned short)(u >> 16);
}
__device__ __forceinline__ float bf2f(unsigned short h) {
  uint32_t u = ((uint32_t)h) << 16;
  return __builtin_bit_cast(float, u);
}

// ============ prep: weight transpose (blocks 0..1535) + adj pack (rest) ====
// (byte-identical to round 7)
__global__ __launch_bounds__(256) void prep_kernel(
    const float* __restrict__ adj,
    const float* __restrict__ W1c, const float* __restrict__ W2c,
    const float* __restrict__ W1j, const float* __restrict__ W2j,
    const float* __restrict__ Wl1, const float* __restrict__ Wl2,
    unsigned short* __restrict__ Wt,
    unsigned long long* __restrict__ bits) {
  const int blk = blockIdx.x;
  if (blk < 1536) {
    const float* Ws[6] = {W1c, W2c, W1j, W2j, Wl1, Wl2};
    const int w = blk >> 8;
    const int n = blk & 255;
    const int k = threadIdx.x;
    Wt[w * 65536 + n * DIM + k] = f2bf(Ws[w][k * DIM + n]);
  } else {
    const float4* __restrict__ adjv = (const float4*)adj;
    const int lane = threadIdx.x & 63;
    const int wv = (blk - 1536) * 4 + (threadIdx.x >> 6);
    const int nwv = 4096 * 4;
    const int total = NN * 32;  // float4-tasks
    for (int t = 4 * wv; t < total; t += 4 * nwv) {
      float4 v0 = adjv[(size_t)((t + 0) >> 5) * 2048 + ((t + 0) & 31) * 64 + lane];
      float4 v1 = adjv[(size_t)((t + 1) >> 5) * 2048 + ((t + 1) & 31) * 64 + lane];
      float4 v2 = adjv[(size_t)((t + 2) >> 5) * 2048 + ((t + 2) & 31) * 64 + lane];
      float4 v3 = adjv[(size_t)((t + 3) >> 5) * 2048 + ((t + 3) & 31) * 64 + lane];
      unsigned long long m00 = __ballot(v0.x != 0.0f);
      unsigned long long m01 = __ballot(v0.y != 0.0f);
      unsigned long long m02 = __ballot(v0.z != 0.0f);
      unsigned long long m03 = __ballot(v0.w != 0.0f);
      unsigned long long m10 = __ballot(v1.x != 0.0f);
      unsigned long long m11 = __ballot(v1.y != 0.0f);
      unsigned long long m12 = __ballot(v1.z != 0.0f);
      unsigned long long m13 = __ballot(v1.w != 0.0f);
      unsigned long long m20 = __ballot(v2.x != 0.0f);
      unsigned long long m21 = __ballot(v2.y != 0.0f);
      unsigned long long m22 = __ballot(v2.z != 0.0f);
      unsigned long long m23 = __ballot(v2.w != 0.0f);
      unsigned long long m30 = __ballot(v3.x != 0.0f);
      unsigned long long m31 = __ballot(v3.y != 0.0f);
      unsigned long long m32 = __ballot(v3.z != 0.0f);
      unsigned long long m33 = __ballot(v3.w != 0.0f);
      if (lane == 0) {
        unsigned long long* p = bits + (size_t)(t >> 5) * NW + (t & 31) * 4;
        p[0]  = m00; p[1]  = m01; p[2]  = m02; p[3]  = m03;
        p[4]  = m10; p[5]  = m11; p[6]  = m12; p[7]  = m13;
        p[8]  = m20; p[9]  = m21; p[10] = m22; p[11] = m23;
        p[12] = m30; p[13] = m31; p[14] = m32; p[15] = m33;
      }
    }
  }
}

// ================= fused: 7-barrier pipeline ========
// Block: 1024 threads = 16 waves, TE=32 edges, 256 blocks (1/CU).
// Each wave owns 16 output cols (1 n-tile) x 2 m-tiles of 16 rows.
// A-frag: row = lane&15, k = (lane>>4)*8 + j
// B-frag: col = lane&15, k = (lane>>4)*8 + j  (register-resident, prefetched)
// C/D:    col = lane&15, row = (lane>>4)*4 + reg   (m89-verified)

#define LDP 264  // 256 + 8 bf16 pad (row stride 528 B, 2-way bank alias = free)

__device__ __forceinline__ void load_w16(const unsigned short* __restrict__ Wt,
                                         bf16x8 w[8], int lane, int wave) {
  const int lr = lane & 15;
  const int kl = (lane >> 4) * 8;
  const int n0 = wave * 16;
#pragma unroll
  for (int kk = 0; kk < 8; ++kk)
    w[kk] = *(const bf16x8*)(Wt + (size_t)(n0 + lr) * DIM + kk * 32 + kl);
}

__device__ __forceinline__ void gemm16(const unsigned short (*src)[LDP],
                                       const bf16x8 w[8],
                                       f32x4 acc[2], int lane) {
  const int lr = lane & 15;
  const int kl = (lane >> 4) * 8;
#pragma unroll
  for (int kk = 0; kk < 8; ++kk) {
    const int k0 = kk * 32 + kl;
    bf16x8 a0 = *(const bf16x8*)(&src[lr][k0]);
    bf16x8 a1 = *(const bf16x8*)(&src[16 + lr][k0]);
    acc[0] = __builtin_amdgcn_mfma_f32_16x16x32_bf16(a0, w[kk], acc[0], 0, 0, 0);
    acc[1] = __builtin_amdgcn_mfma_f32_16x16x32_bf16(a1, w[kk], acc[1], 0, 0, 0);
  }
}

__device__ __forceinline__ void epilogue16(f32x4 acc[2], float bb, bool relu,
                                           unsigned short (*dst)[LDP],
                                           int lane, int wave) {
  const int lc = lane & 15;
  const int rg = (lane >> 4) * 4;
  const int col = wave * 16 + lc;
#pragma unroll
  for (int m = 0; m < 2; ++m)
#pragma unroll
    for (int q = 0; q < 4; ++q) {
      float v = acc[m][q] + bb;
      if (relu) v = fmaxf(v, 0.f);
      dst[m * 16 + rg + q][col] = f2bf(v);
    }
}

__global__ __launch_bounds__(1024) void fused_kernel(
    const float* __restrict__ x,
    const unsigned long long* __restrict__ bits,
    const int* __restrict__ tar,
    const unsigned short* __restrict__ Wt,
    const float* __restrict__ b1c, const float* __restrict__ b2c,
    const float* __restrict__ b1j, const float* __restrict__ b2j,
    const float* __restrict__ bl1, const float* __restrict__ bl2,
    const float* __restrict__ Wout, const float* __restrict__ bout,
    float* __restrict__ out) {
  __shared__ unsigned short lA[TE][LDP];  // xcn -> h
  __shared__ unsigned short lB[TE][LDP];  // U2 -> h2
  __shared__ unsigned short lC[TE][LDP];  // xixj -> U1
  __shared__ int hits[TE][HCAP];
  __shared__ int nh[TE];
  __shared__ float sPart[16][TE];         // per-wave GEMV partials

  const int tid = threadIdx.x;
  const int lane = tid & 63;
  const int wave = tid >> 6;  // 0..15
  const int e0 = blockIdx.x * TE;

  // ---- per-lane constant preloads ----
  const int lc = lane & 15;
  const int c0 = wave * 16 + lc;
  const float vb1c = b1c[c0];
  const float vb1j = b1j[c0];
  const float vb2 = b2c[c0] + b2j[c0];
  const float vbl1 = bl1[c0];
  const float vbl2 = bl2[c0];
  const float vwout = Wout[c0];
  const float vbout = bout[0];

  if (tid < TE) nh[tid] = 0;

  // ---- (a) bits words -> regs (32 thr/edge, 4 words each endpoint) ----
  const int e_a = tid >> 5;
  const int t32 = tid & 31;
  unsigned long long bw_i[4], bw_j[4];
  {
    const int ia = tar[e0 + e_a];
    const int ja = tar[NE + e0 + e_a];
    const unsigned long long* bi = bits + (size_t)ia * NW + t32 * 4;
    const unsigned long long* bj = bits + (size_t)ja * NW + t32 * 4;
#pragma unroll
    for (int q = 0; q < 4; ++q) { bw_i[q] = bi[q]; bw_j[q] = bj[q]; }
  }

  // ---- (b) xixj -> lC ; then issue W1c/W1j prefetch ----
  {
    const int col = tid & 255;
    const int sub = tid >> 8;  // 0..3 -> 8 edges each
    float vi[8], vj[8];
#pragma unroll
    for (int p = 0; p < 8; ++p) {
      const int e = sub * 8 + p;
      vi[p] = x[(size_t)tar[e0 + e] * DIM + col];
      vj[p] = x[(size_t)tar[NE + e0 + e] * DIM + col];
    }
#pragma unroll
    for (int p = 0; p < 8; ++p)
      lC[sub * 8 + p][col] = f2bf(vi[p] * vj[p]);
  }
  bf16x8 wX[8], wY[8];
  load_w16(Wt + 2 * 65536, wX, lane, wave);  // W1j (used phase 3)
  load_w16(Wt + 0 * 65536, wY, lane, wave);  // W1c (used phase 4)
  __syncthreads();  // [1] nh zeroed; lC ready

  // ---- (c) intersect (pure VALU + LDS atomics; weight loads in flight) ----
#pragma unroll
  for (int q = 0; q < 4; ++q) {
    unsigned long long m = bw_i[q] & bw_j[q];
    const int base = t32 << 8;
    while (m) {
      int b = __builtin_ctzll(m);
      m &= m - 1;
      int idx = atomicAdd(&nh[e_a], 1);
      if (idx < HCAP) hits[e_a][idx] = base + (b << 2) + q;  // node id
    }
  }
  __syncthreads();  // [2] hits ready

  f32x4 acc[2];
  const f32x4 z4 = {0.f, 0.f, 0.f, 0.f};

  // ---- P3: xcn gathers -> lA  ∥  U2 = relu(xixj @ W1j + b1j) -> lB ----
  {
    const int col = tid & 255;
    const int sub = tid >> 8;
    float xc[8];
#pragma unroll
    for (int p = 0; p < 8; ++p) {
      const int e = sub * 8 + p;
      const int n = nh[e] < HCAP ? nh[e] : HCAP;
      float s = 0.f;
      for (int h = 0; h < n; ++h)
        s += x[(size_t)hits[e][h] * DIM + col];
      xc[p] = s;
    }
    acc[0] = z4; acc[1] = z4;
    gemm16(lC, wX, acc, lane);                 // U2 (lC = xixj)
    load_w16(Wt + 1 * 65536, wX, lane, wave);  // reload wX = W2c
    epilogue16(acc, vb1j, true, lB, lane, wave);
#pragma unroll
    for (int p = 0; p < 8; ++p)
      lA[sub * 8 + p][col] = f2bf(xc[p]);
  }
  __syncthreads();  // [3] lA = xcn, lB = U2

  // ---- P4: U1 = relu(xcn @ W1c + b1c) -> lC ; reload wY = W2j ----
  acc[0] = z4; acc[1] = z4;
  gemm16(lA, wY, acc, lane);
  load_w16(Wt + 3 * 65536, wY, lane, wave);
  epilogue16(acc, vb1c, true, lC, lane, wave);
  __syncthreads();  // [4] lC = U1

  // ---- P5: h = U1@W2c + U2@W2j + b2 -> lA (no relu) ; wX=Wl1, wY=Wl2 ----
  acc[0] = z4; acc[1] = z4;
  gemm16(lC, wX, acc, lane);
  gemm16(lB, wY, acc, lane);
  load_w16(Wt + 4 * 65536, wX, lane, wave);  // Wl1
  load_w16(Wt + 5 * 65536, wY, lane, wave);  // Wl2
  epilogue16(acc, vb2, false, lA, lane, wave);
  __syncthreads();  // [5] lA = h

  // ---- P6: h2 = relu(h @ Wl1 + bl1) -> lB ----
  acc[0] = z4; acc[1] = z4;
  gemm16(lA, wX, acc, lane);
  epilogue16(acc, vbl1, true, lB, lane, wave);
  __syncthreads();  // [6] lB = h2

  // ---- P7: h3 = relu(h2 @ Wl2 + bl2) in regs ; GEMV partial reduce ----
  acc[0] = z4; acc[1] = z4;
  gemm16(lB, wY, acc, lane);
  {
    const int rg = (lane >> 4) * 4;
    float v[2][4];
#pragma unroll
    for (int m = 0; m < 2; ++m)
#pragma unroll
      for (int q = 0; q < 4; ++q) {
        float h3 = fmaxf(acc[m][q] + vbl2, 0.f);
        v[m][q] = h3 * vwout;
      }
    // butterfly over the 16-lane col group (same 8 rows per group)
#pragma unroll
    for (int o = 1; o < 16; o <<= 1)
#pragma unroll
      for (int m = 0; m < 2; ++m)
#pragma unroll
        for (int q = 0; q < 4; ++q)
          v[m][q] += __shfl_xor(v[m][q], o);
    if (lc == 0) {
#pragma unroll
      for (int m = 0; m < 2; ++m)
#pragma unroll
        for (int q = 0; q < 4; ++q)
          sPart[wave][m * 16 + rg + q] = v[m][q];
    }
  }
  __syncthreads();  // [7] sPart ready

  // ---- final: deterministic 16-way sum ----
  if (tid < TE) {
    float s = 0.f;
#pragma unroll
    for (int w = 0; w < 16; ++w) s += sPart[w][tid];
    out[e0 + tid] = s + vbout;
  }
}

extern "C" void kernel_launch(void* const* d_in, const int* in_sizes, int n_in,
                              void* d_out, int out_size, void* d_ws, size_t ws_size,
                              hipStream_t stream) {
  const float* x    = (const float*)d_in[0];
  const float* adj  = (const float*)d_in[1];
  const int*   tar  = (const int*)d_in[2];
  const float* W1c  = (const float*)d_in[3];
  const float* b1c  = (const float*)d_in[4];
  const float* W2c  = (const float*)d_in[5];
  const float* b2c  = (const float*)d_in[6];
  const float* W1j  = (const float*)d_in[7];
  const float* b1j  = (const float*)d_in[8];
  const float* W2j  = (const float*)d_in[9];
  const float* b2j  = (const float*)d_in[10];
  const float* Wl1  = (const float*)d_in[11];
  const float* bl1  = (const float*)d_in[12];
  const float* Wl2  = (const float*)d_in[13];
  const float* bl2  = (const float*)d_in[14];
  const float* Wout = (const float*)d_in[15];
  const float* bout = (const float*)d_in[16];

  char* ws = (char*)d_ws;
  unsigned short*     Wt   = (unsigned short*)(ws);                  // 768 KB
  unsigned long long* bits = (unsigned long long*)(ws + (1u << 20)); // 8 MB

  prep_kernel<<<1536 + 4096, 256, 0, stream>>>(adj, W1c, W2c, W1j, W2j, Wl1,
                                               Wl2, Wt, bits);

  fused_kernel<<<NE / TE, 1024, 0, stream>>>(x, bits, tar, Wt, b1c, b2c, b1j,
                                             b2j, bl1, bl2, Wout, bout,
                                             (float*)d_out);
}